// Round 1
// baseline (416.000 us; speedup 1.0000x reference)
//
#include <hip/hip_runtime.h>

// Problem constants (from reference): B=8, N=100000, C=80 classes, row = 5+C = 85 f32.
// Output layout (tuple concat, flat): detections [B*N*7] f32, then valid [B*N] (as f32 0/1).

#define ROW      85
#define NCLS     80
#define TILE     64      // rows per block
#define THREADS  64
#define CONF_THRES 0.05f

__global__ __launch_bounds__(THREADS) void detect_kernel(
    const float* __restrict__ pred,   // [rows][85]
    float* __restrict__ det,          // [rows][7]
    float* __restrict__ valid,        // [rows]
    int rows)
{
    __shared__ float lds[TILE * ROW];        // 5440 f32 = 21760 B, 16B-aligned tiles
    __shared__ float lds_out[TILE * 7];      // 448 f32 staging for coalesced det writes

    const int tile0 = blockIdx.x * TILE;
    const int nrows = min(TILE, rows - tile0);
    if (nrows <= 0) return;

    if (nrows == TILE) {
        // Fast path: whole tile, 16B-aligned (64*85*4 = 21760 bytes per tile).
        const float4* __restrict__ src = (const float4*)(pred + (size_t)tile0 * ROW);
        float4* dst = (float4*)lds;
        // 1360 float4 per tile
        for (int i = threadIdx.x; i < (TILE * ROW) / 4; i += THREADS)
            dst[i] = src[i];
    } else {
        const float* __restrict__ src = pred + (size_t)tile0 * ROW;
        const int n = nrows * ROW;
        for (int i = threadIdx.x; i < n; i += THREADS)
            lds[i] = src[i];
    }
    __syncthreads();

    const int t = threadIdx.x;
    if (t < nrows) {
        const float* row = lds + t * ROW;   // 2-way LDS bank alias across lanes: free
        const float x = row[0], y = row[1], w = row[2], h = row[3], conf = row[4];

        float best = row[5];
        int bidx = 0;
        #pragma unroll
        for (int k = 1; k < NCLS; ++k) {
            const float s = row[5 + k];
            if (s > best) { best = s; bidx = k; }   // strict > => first-max, matches jnp.argmax
        }

        const float v = (conf >= CONF_THRES) ? 1.0f : 0.0f;
        float* o = lds_out + t * 7;
        o[0] = x * v;
        o[1] = y * v;
        o[2] = w * v;
        o[3] = h * v;
        o[4] = conf * v;
        o[5] = best * v;
        o[6] = (float)bidx * v;

        valid[tile0 + t] = v;   // coalesced dword store
    }
    __syncthreads();

    // Coalesced detections write: 448 floats = 112 float4 per full tile.
    if (nrows == TILE) {
        const float4* s4 = (const float4*)lds_out;
        float4* d4 = (float4*)(det + (size_t)tile0 * 7);   // 64*7*4 = 1792 B per tile, 16B-aligned
        for (int i = threadIdx.x; i < (TILE * 7) / 4; i += THREADS)
            d4[i] = s4[i];
    } else {
        float* d = det + (size_t)tile0 * 7;
        const int n = nrows * 7;
        for (int i = threadIdx.x; i < n; i += THREADS)
            d[i] = lds_out[i];
    }
}

extern "C" void kernel_launch(void* const* d_in, const int* in_sizes, int n_in,
                              void* d_out, int out_size, void* d_ws, size_t ws_size,
                              hipStream_t stream)
{
    const float* pred = (const float*)d_in[0];
    const int rows = in_sizes[0] / ROW;          // 8*100000 = 800000
    float* out = (float*)d_out;
    float* det = out;                            // rows*7 floats
    float* valid = out + (size_t)rows * 7;       // rows floats

    const int blocks = (rows + TILE - 1) / TILE; // 12500
    detect_kernel<<<blocks, THREADS, 0, stream>>>(pred, det, valid, rows);
}

// Round 2
// 363.379 us; speedup vs baseline: 1.1448x; 1.1448x over previous
//
#include <hip/hip_runtime.h>

// B=8, N=100000, C=80: 800000 rows of 85 f32.
// Out: det [rows*7] f32, then valid [rows] f32 (0/1).

#define ROW      85
#define NCLS     80
#define TILE     64      // rows per block
#define THREADS  128     // 2 waves; 2 lanes cooperate per row
#define CONF_THRES 0.05f

__global__ __launch_bounds__(THREADS) void detect_kernel(
    const float* __restrict__ pred,   // [rows][85]
    float* __restrict__ det,          // [rows][7]
    float* __restrict__ valid,        // [rows]
    int rows)
{
    __shared__ float lds[TILE * ROW];   // 21760 B -> ~7 blocks/CU = 14 waves/CU

    const int tile0 = blockIdx.x * TILE;
    const int nrows = min(TILE, rows - tile0);
    if (nrows <= 0) return;

    if (nrows == TILE) {
        // Fully coalesced float4 staging: 1360 float4 = 21760 B, tile base 16B-aligned.
        const float4* __restrict__ src = (const float4*)(pred + (size_t)tile0 * ROW);
        float4* dst = (float4*)lds;
        #pragma unroll
        for (int it = 0; it < 10; ++it)
            dst[threadIdx.x + THREADS * it] = src[threadIdx.x + THREADS * it];
        if (threadIdx.x < 80)
            dst[1280 + threadIdx.x] = src[1280 + threadIdx.x];
    } else {
        const float* __restrict__ src = pred + (size_t)tile0 * ROW;
        for (int i = threadIdx.x; i < nrows * ROW; i += THREADS)
            lds[i] = src[i];
    }
    __syncthreads();

    // Wave w owns rows [w*32, w*32+32); lane<32 handles classes 0..39,
    // lane>=32 handles classes 40..79 of the same row. Combine via shfl_xor(32).
    const int wave      = threadIdx.x >> 6;
    const int lane      = threadIdx.x & 63;
    const int half      = lane >> 5;
    const int row_local = wave * 32 + (lane & 31);
    const float* row    = lds + row_local * ROW;

    const int kbase = half * 40;          // 0 or 40 — non-divergent
    float best = row[5 + kbase];
    int   bidx = kbase;
    #pragma unroll
    for (int j = 1; j < 40; ++j) {
        const float s = row[5 + kbase + j];
        if (s > best) { best = s; bidx = kbase + j; }   // strict > = first-max
    }

    const float obest = __shfl_xor(best, 32);
    const int   oidx  = __shfl_xor(bidx, 32);
    // For half==0 lanes: partner indices are all larger, strict > keeps first-max.
    if (obest > best) { best = obest; bidx = oidx; }

    if (half == 0 && row_local < nrows) {
        const float x = row[0], y = row[1], w = row[2], h = row[3], conf = row[4];
        const float v = (conf >= CONF_THRES) ? 1.0f : 0.0f;
        const int   r = tile0 + row_local;
        float* o = det + (size_t)r * 7;
        o[0] = x * v;
        o[1] = y * v;
        o[2] = w * v;
        o[3] = h * v;
        o[4] = conf * v;
        o[5] = best * v;
        o[6] = (float)bidx * v;
        valid[r] = v;
    }
}

extern "C" void kernel_launch(void* const* d_in, const int* in_sizes, int n_in,
                              void* d_out, int out_size, void* d_ws, size_t ws_size,
                              hipStream_t stream)
{
    const float* pred = (const float*)d_in[0];
    const int rows = in_sizes[0] / ROW;          // 800000
    float* out = (float*)d_out;
    float* det = out;                            // rows*7
    float* valid = out + (size_t)rows * 7;       // rows

    const int blocks = (rows + TILE - 1) / TILE; // 12500
    detect_kernel<<<blocks, THREADS, 0, stream>>>(pred, det, valid, rows);
}